// Round 2
// baseline (484.562 us; speedup 1.0000x reference)
//
#include <hip/hip_runtime.h>
#include <hip/hip_bf16.h>
#include <stdint.h>

typedef __attribute__((ext_vector_type(8))) short bfx8;
typedef __attribute__((ext_vector_type(4))) float f32x4;
typedef __attribute__((ext_vector_type(4))) unsigned short us4;

#define SCALE_ATT 0.125f

__device__ __forceinline__ unsigned short f2bf(float f) {
  union { float f; unsigned u; } a; a.f = f;
  unsigned r = a.u + 0x7fffu + ((a.u >> 16) & 1u);
  return (unsigned short)(r >> 16);
}

__device__ __forceinline__ void gll16(const void* g, void* l) {
  __builtin_amdgcn_global_load_lds(
      (__attribute__((address_space(1))) void*)(g),
      (__attribute__((address_space(3))) void*)(l), 16, 0, 0);
}

// ---------------- prepass: x f32 -> bf16 ----------------
__global__ __launch_bounds__(256) void cvt_x(const float* __restrict__ x,
                                             unsigned short* __restrict__ xb, int n4) {
  int i = blockIdx.x * blockDim.x + threadIdx.x;
  int stride = gridDim.x * blockDim.x;
  const float4* x4 = (const float4*)x;
  for (; i < n4; i += stride) {
    float4 v = x4[i];
    us4 o;
    o[0] = f2bf(v.x); o[1] = f2bf(v.y); o[2] = f2bf(v.z); o[3] = f2bf(v.w);
    *(us4*)&xb[(size_t)i * 4] = o;
  }
}

// ---------------- prepass: W f32 [K][N] -> Wt bf16 [N][K] (transpose) ----------------
__global__ __launch_bounds__(256) void cvt_w(const float* __restrict__ W0, const float* __restrict__ W1,
                                             const float* __restrict__ W2, const float* __restrict__ W3,
                                             unsigned short* __restrict__ T0, unsigned short* __restrict__ T1,
                                             unsigned short* __restrict__ T2, unsigned short* __restrict__ T3) {
  const float* W; unsigned short* T;
  switch (blockIdx.z) {
    case 0: W = W0; T = T0; break;
    case 1: W = W1; T = T1; break;
    case 2: W = W2; T = T2; break;
    default: W = W3; T = T3; break;
  }
  __shared__ unsigned short Ts[64][68];
  int k0 = blockIdx.x * 64, n0 = blockIdx.y * 64;
  int t = threadIdx.x;
  int lrow = t >> 4, c4 = t & 15;
  #pragma unroll
  for (int i = 0; i < 4; i++) {
    int row = lrow + i * 16;                              // k within tile
    float4 v = *(const float4*)&W[(size_t)(k0 + row) * 1024 + n0 + c4 * 4];
    Ts[c4 * 4 + 0][row] = f2bf(v.x);
    Ts[c4 * 4 + 1][row] = f2bf(v.y);
    Ts[c4 * 4 + 2][row] = f2bf(v.z);
    Ts[c4 * 4 + 3][row] = f2bf(v.w);
  }
  __syncthreads();
  #pragma unroll
  for (int i = 0; i < 4; i++) {
    int nrow = lrow + i * 16;                             // n within tile
    us4 v = *(const us4*)&Ts[nrow][c4 * 4];
    *(us4*)&T[(size_t)(n0 + nrow) * 1024 + k0 + c4 * 4] = v;
  }
}

// ---------------- fused QKV GEMM: [16384x1024]bf16 x Wt[1024x1024]bf16 -> bf16 ----------------
__global__ __launch_bounds__(256) void gemm_qkv(
    const unsigned short* __restrict__ A,
    const unsigned short* __restrict__ Wtq, const unsigned short* __restrict__ Wtk,
    const unsigned short* __restrict__ Wtv,
    unsigned short* __restrict__ Qb, unsigned short* __restrict__ Kb, unsigned short* __restrict__ Vb) {
  __shared__ unsigned short As[128 * 32];
  __shared__ unsigned short Bs[128 * 32];
  int t = threadIdx.x;
  int w = t >> 6, l = t & 63;
  int wr = w >> 1, wc = w & 1;
  int lr = l & 15, lh = l >> 4;
  int bm = blockIdx.x, bn = blockIdx.y;
  int sel = bn >> 3;
  int n0 = (bn & 7) * 128;
  const unsigned short* Bt = sel == 0 ? Wtq : (sel == 1 ? Wtk : Wtv);
  unsigned short* Out = sel == 0 ? Qb : (sel == 1 ? Kb : Vb);

  const unsigned short* Ag = A + (size_t)(bm * 128) * 1024;
  const unsigned short* Bg = Bt + (size_t)n0 * 1024;

  f32x4 acc[4][4];
  #pragma unroll
  for (int i = 0; i < 4; i++)
    #pragma unroll
    for (int j = 0; j < 4; j++) acc[i][j] = (f32x4){0.f, 0.f, 0.f, 0.f};

  int srow = w * 32 + (l >> 2);
  int sk = (l & 3) * 8;

  for (int k0 = 0; k0 < 1024; k0 += 32) {
    gll16(Ag + (size_t)srow * 1024 + k0 + sk,        As + w * 1024);
    gll16(Ag + (size_t)(srow + 16) * 1024 + k0 + sk, As + w * 1024 + 512);
    gll16(Bg + (size_t)srow * 1024 + k0 + sk,        Bs + w * 1024);
    gll16(Bg + (size_t)(srow + 16) * 1024 + k0 + sk, Bs + w * 1024 + 512);
    __syncthreads();
    bfx8 af[4], bfv[4];
    #pragma unroll
    for (int rt = 0; rt < 4; rt++) af[rt] = *(const bfx8*)&As[(wr * 64 + rt * 16 + lr) * 32 + lh * 8];
    #pragma unroll
    for (int ct = 0; ct < 4; ct++) bfv[ct] = *(const bfx8*)&Bs[(wc * 64 + ct * 16 + lr) * 32 + lh * 8];
    #pragma unroll
    for (int rt = 0; rt < 4; rt++)
      #pragma unroll
      for (int ct = 0; ct < 4; ct++)
        acc[rt][ct] = __builtin_amdgcn_mfma_f32_16x16x32_bf16(af[rt], bfv[ct], acc[rt][ct], 0, 0, 0);
    __syncthreads();
  }

  int row0 = bm * 128 + wr * 64;
  #pragma unroll
  for (int rt = 0; rt < 4; rt++)
    #pragma unroll
    for (int ct = 0; ct < 4; ct++)
      #pragma unroll
      for (int j = 0; j < 4; j++) {
        int r = row0 + rt * 16 + lh * 4 + j;
        int c = n0 + wc * 64 + ct * 16 + lr;
        Out[(size_t)r * 1024 + c] = f2bf(acc[rt][ct][j]);
      }
}

// ---------------- output projection GEMM + bias -> f32 ----------------
__global__ __launch_bounds__(256) void gemm_proj(
    const unsigned short* __restrict__ A, const unsigned short* __restrict__ Bt,
    const float* __restrict__ bias, float* __restrict__ Out) {
  __shared__ unsigned short As[128 * 32];
  __shared__ unsigned short Bs[128 * 32];
  int t = threadIdx.x;
  int w = t >> 6, l = t & 63;
  int wr = w >> 1, wc = w & 1;
  int lr = l & 15, lh = l >> 4;
  int bm = blockIdx.x, bn = blockIdx.y;
  int n0 = bn * 128;
  const unsigned short* Ag = A + (size_t)(bm * 128) * 1024;
  const unsigned short* Bg = Bt + (size_t)n0 * 1024;

  f32x4 acc[4][4];
  #pragma unroll
  for (int i = 0; i < 4; i++)
    #pragma unroll
    for (int j = 0; j < 4; j++) acc[i][j] = (f32x4){0.f, 0.f, 0.f, 0.f};

  int srow = w * 32 + (l >> 2);
  int sk = (l & 3) * 8;

  for (int k0 = 0; k0 < 1024; k0 += 32) {
    gll16(Ag + (size_t)srow * 1024 + k0 + sk,        As + w * 1024);
    gll16(Ag + (size_t)(srow + 16) * 1024 + k0 + sk, As + w * 1024 + 512);
    gll16(Bg + (size_t)srow * 1024 + k0 + sk,        Bs + w * 1024);
    gll16(Bg + (size_t)(srow + 16) * 1024 + k0 + sk, Bs + w * 1024 + 512);
    __syncthreads();
    bfx8 af[4], bfv[4];
    #pragma unroll
    for (int rt = 0; rt < 4; rt++) af[rt] = *(const bfx8*)&As[(wr * 64 + rt * 16 + lr) * 32 + lh * 8];
    #pragma unroll
    for (int ct = 0; ct < 4; ct++) bfv[ct] = *(const bfx8*)&Bs[(wc * 64 + ct * 16 + lr) * 32 + lh * 8];
    #pragma unroll
    for (int rt = 0; rt < 4; rt++)
      #pragma unroll
      for (int ct = 0; ct < 4; ct++)
        acc[rt][ct] = __builtin_amdgcn_mfma_f32_16x16x32_bf16(af[rt], bfv[ct], acc[rt][ct], 0, 0, 0);
    __syncthreads();
  }

  float bv[4];
  #pragma unroll
  for (int ct = 0; ct < 4; ct++) bv[ct] = bias[n0 + wc * 64 + ct * 16 + lr];

  int row0 = bm * 128 + wr * 64;
  #pragma unroll
  for (int rt = 0; rt < 4; rt++)
    #pragma unroll
    for (int ct = 0; ct < 4; ct++)
      #pragma unroll
      for (int j = 0; j < 4; j++) {
        int r = row0 + rt * 16 + lh * 4 + j;
        int c = n0 + wc * 64 + ct * 16 + lr;
        Out[(size_t)r * 1024 + c] = acc[rt][ct][j] + bv[ct];
      }
}

// ---------------- causal attention per (b,h) ----------------
__global__ __launch_bounds__(256) void attn_kernel(
    const unsigned short* __restrict__ Qb, const unsigned short* __restrict__ Kb,
    const unsigned short* __restrict__ Vb, unsigned short* __restrict__ Ab) {
  __shared__ unsigned short Ks[256][72];   // K rows, padded (144B stride, ~2-way)
  __shared__ unsigned short Vt[64][264];   // V transposed [d][k], padded (528B stride)
  __shared__ float Ss[64][260];            // scores f32; reused as P bf16 (same byte rows)
  __shared__ float rsum[64];

  int t = threadIdx.x;
  int w = t >> 6, l = t & 63;
  int lr = l & 15, lh = l >> 4;
  int bh = blockIdx.x;
  size_t rowbase = (size_t)(bh >> 4) * 256 * 1024 + (size_t)(bh & 15) * 64;

  // stage K row-major, V transposed
  {
    int rr = t >> 3;      // 0..31
    int part = t & 7;     // 16B chunk within a 64-elem row
    for (int i = 0; i < 8; i++) {
      int row = i * 32 + rr;
      bfx8 kv = *(const bfx8*)(Kb + rowbase + (size_t)row * 1024 + part * 8);
      *(bfx8*)&Ks[row][part * 8] = kv;
      bfx8 vv = *(const bfx8*)(Vb + rowbase + (size_t)row * 1024 + part * 8);
      #pragma unroll
      for (int e = 0; e < 8; e++) Vt[part * 8 + e][row] = (unsigned short)vv[e];
    }
  }
  __syncthreads();

  for (int qt = 0; qt < 4; qt++) {
    int q0 = qt * 64;
    // Q fragments for this wave's 16-row tile (rows q0 + w*16 .. +15)
    const unsigned short* Qrow = Qb + rowbase + (size_t)(q0 + w * 16 + lr) * 1024;
    bfx8 aq0 = *(const bfx8*)(Qrow + lh * 8);
    bfx8 aq1 = *(const bfx8*)(Qrow + 32 + lh * 8);

    // S = Q K^T (skip fully-masked col tiles)
    int nct = qt * 4 + w + 1;
    for (int ct = 0; ct < nct; ct++) {
      bfx8 bk0 = *(const bfx8*)&Ks[ct * 16 + lr][lh * 8];
      bfx8 bk1 = *(const bfx8*)&Ks[ct * 16 + lr][32 + lh * 8];
      f32x4 s = (f32x4){0.f, 0.f, 0.f, 0.f};
      s = __builtin_amdgcn_mfma_f32_16x16x32_bf16(aq0, bk0, s, 0, 0, 0);
      s = __builtin_amdgcn_mfma_f32_16x16x32_bf16(aq1, bk1, s, 0, 0, 0);
      #pragma unroll
      for (int j = 0; j < 4; j++) Ss[w * 16 + lh * 4 + j][ct * 16 + lr] = s[j];
    }
    __syncthreads();

    // softmax (causal); P bf16 packed pairwise into the same f32 rows (in-place, ascending-safe)
    if (t < 64) {
      int r = t, q = q0 + r;
      float m = -1e30f;
      for (int k = 0; k <= q; k++) m = fmaxf(m, Ss[r][k]);
      float sum = 0.f;
      for (int k2 = 0; k2 <= q; k2 += 2) {
        float e0 = __expf((Ss[r][k2] - m) * SCALE_ATT);
        float e1 = (k2 + 1 <= q) ? __expf((Ss[r][k2 + 1] - m) * SCALE_ATT) : 0.f;
        sum += e0 + e1;
        unsigned pu = (unsigned)f2bf(e0) | ((unsigned)f2bf(e1) << 16);
        union { unsigned u; float f; } pf; pf.u = pu;
        Ss[r][k2 >> 1] = pf.f;               // clobbers only already-consumed cols
      }
      for (int s8 = (q >> 1) + 1; s8 < 128; s8++) Ss[r][s8] = 0.f;
      rsum[r] = 1.0f / sum;
    }
    __syncthreads();

    // O = P V  (1/sum folded into epilogue)
    const unsigned short* P = (const unsigned short*)&Ss[0][0];
    f32x4 oc[4];
    #pragma unroll
    for (int ct = 0; ct < 4; ct++) oc[ct] = (f32x4){0.f, 0.f, 0.f, 0.f};
    int kcmax = (q0 + w * 16 + 15) >> 5;
    for (int kc = 0; kc <= kcmax; kc++) {
      bfx8 pa = *(const bfx8*)&P[(size_t)(w * 16 + lr) * 520 + kc * 32 + lh * 8];
      #pragma unroll
      for (int ct = 0; ct < 4; ct++) {
        bfx8 vbf = *(const bfx8*)&Vt[ct * 16 + lr][kc * 32 + lh * 8];
        oc[ct] = __builtin_amdgcn_mfma_f32_16x16x32_bf16(pa, vbf, oc[ct], 0, 0, 0);
      }
    }
    #pragma unroll
    for (int ct = 0; ct < 4; ct++)
      #pragma unroll
      for (int j = 0; j < 4; j++) {
        int rloc = w * 16 + lh * 4 + j;
        float v = oc[ct][j] * rsum[rloc];
        Ab[rowbase + (size_t)(q0 + rloc) * 1024 + ct * 16 + lr] = f2bf(v);
      }
    __syncthreads();
  }
}

extern "C" void kernel_launch(void* const* d_in, const int* in_sizes, int n_in,
                              void* d_out, int out_size, void* d_ws, size_t ws_size,
                              hipStream_t stream) {
  const float* x  = (const float*)d_in[0];
  const float* Wq = (const float*)d_in[1];
  const float* Wk = (const float*)d_in[2];
  const float* Wv = (const float*)d_in[3];
  const float* Wo = (const float*)d_in[4];
  const float* bo = (const float*)d_in[5];
  float* out = (float*)d_out;

  char* ws = (char*)d_ws;
  unsigned short* xb  = (unsigned short*)(ws);                          // 32MB (reused as Ab)
  unsigned short* Wtq = (unsigned short*)(ws + (size_t)(32u << 20));    // 2MB
  unsigned short* Wtk = (unsigned short*)(ws + (size_t)(34u << 20));
  unsigned short* Wtv = (unsigned short*)(ws + (size_t)(36u << 20));
  unsigned short* Wto = (unsigned short*)(ws + (size_t)(38u << 20));
  unsigned short* Qb  = (unsigned short*)(ws + (size_t)(40u << 20));    // 32MB
  unsigned short* Kb  = (unsigned short*)(ws + (size_t)(72u << 20));    // 32MB
  unsigned short* Vb  = (unsigned short*)(ws + (size_t)(104u << 20));   // 32MB
  unsigned short* Ab  = xb;  // x dead after gemm_qkv

  cvt_x<<<2048, 256, 0, stream>>>(x, xb, 4194304);
  cvt_w<<<dim3(16, 16, 4), 256, 0, stream>>>(Wq, Wk, Wv, Wo, Wtq, Wtk, Wtv, Wto);
  gemm_qkv<<<dim3(128, 24), 256, 0, stream>>>(xb, Wtq, Wtk, Wtv, Qb, Kb, Vb);
  attn_kernel<<<1024, 256, 0, stream>>>(Qb, Kb, Vb, Ab);
  gemm_proj<<<dim3(128, 8), 256, 0, stream>>>(Ab, Wto, bo, out);
}

// Round 4
// 257.252 us; speedup vs baseline: 1.8836x; 1.8836x over previous
//
#include <hip/hip_runtime.h>
#include <hip/hip_bf16.h>
#include <stdint.h>

typedef __attribute__((ext_vector_type(8))) short bfx8;
typedef __attribute__((ext_vector_type(4))) short bfx4;
typedef __attribute__((ext_vector_type(4))) float f32x4;
typedef __attribute__((ext_vector_type(4))) unsigned short us4;

#define SCALE_ATT 0.125f

__device__ __forceinline__ unsigned short f2bf(float f) {
  union { float f; unsigned u; } a; a.f = f;
  unsigned r = a.u + 0x7fffu + ((a.u >> 16) & 1u);
  return (unsigned short)(r >> 16);
}

__device__ __forceinline__ void gll16(const void* g, void* l) {
  __builtin_amdgcn_global_load_lds(
      (__attribute__((address_space(1))) void*)(g),
      (__attribute__((address_space(3))) void*)(l), 16, 0, 0);
}

__device__ __forceinline__ bfx8 ld2x64(const unsigned short* p) {
  bfx4 lo = *(const bfx4*)p;
  bfx4 hi = *(const bfx4*)(p + 4);
  return __builtin_shufflevector(lo, hi, 0, 1, 2, 3, 4, 5, 6, 7);
}

// ---------------- prepass: x f32 -> bf16 ----------------
__global__ __launch_bounds__(256) void cvt_x(const float* __restrict__ x,
                                             unsigned short* __restrict__ xb, int n4) {
  int i = blockIdx.x * blockDim.x + threadIdx.x;
  int stride = gridDim.x * blockDim.x;
  const float4* x4 = (const float4*)x;
  for (; i < n4; i += stride) {
    float4 v = x4[i];
    us4 o;
    o[0] = f2bf(v.x); o[1] = f2bf(v.y); o[2] = f2bf(v.z); o[3] = f2bf(v.w);
    *(us4*)&xb[(size_t)i * 4] = o;
  }
}

// ---------------- prepass: W f32 [K][N] -> Wt bf16 [N][K] (transpose) ----------------
__global__ __launch_bounds__(256) void cvt_w(const float* __restrict__ W0, const float* __restrict__ W1,
                                             const float* __restrict__ W2, const float* __restrict__ W3,
                                             unsigned short* __restrict__ T0, unsigned short* __restrict__ T1,
                                             unsigned short* __restrict__ T2, unsigned short* __restrict__ T3) {
  const float* W; unsigned short* T;
  switch (blockIdx.z) {
    case 0: W = W0; T = T0; break;
    case 1: W = W1; T = T1; break;
    case 2: W = W2; T = T2; break;
    default: W = W3; T = T3; break;
  }
  __shared__ unsigned short Ts[64][68];
  int k0 = blockIdx.x * 64, n0 = blockIdx.y * 64;
  int t = threadIdx.x;
  int lrow = t >> 4, c4 = t & 15;
  #pragma unroll
  for (int i = 0; i < 4; i++) {
    int row = lrow + i * 16;                              // k within tile
    float4 v = *(const float4*)&W[(size_t)(k0 + row) * 1024 + n0 + c4 * 4];
    Ts[c4 * 4 + 0][row] = f2bf(v.x);
    Ts[c4 * 4 + 1][row] = f2bf(v.y);
    Ts[c4 * 4 + 2][row] = f2bf(v.z);
    Ts[c4 * 4 + 3][row] = f2bf(v.w);
  }
  __syncthreads();
  #pragma unroll
  for (int i = 0; i < 4; i++) {
    int nrow = lrow + i * 16;                             // n within tile
    us4 v = *(const us4*)&Ts[nrow][c4 * 4];
    *(us4*)&T[(size_t)(n0 + nrow) * 1024 + k0 + c4 * 4] = v;
  }
}

// ---------------- fused QKV GEMM: [16384x1024]bf16 x Wt[1024x1024]bf16 -> bf16 ----------------
__global__ __launch_bounds__(256) void gemm_qkv(
    const unsigned short* __restrict__ A,
    const unsigned short* __restrict__ Wtq, const unsigned short* __restrict__ Wtk,
    const unsigned short* __restrict__ Wtv,
    unsigned short* __restrict__ Qb, unsigned short* __restrict__ Kb, unsigned short* __restrict__ Vb) {
  __shared__ unsigned short As[128 * 32];
  __shared__ unsigned short Bs[128 * 32];
  int t = threadIdx.x;
  int w = t >> 6, l = t & 63;
  int wr = w >> 1, wc = w & 1;
  int lr = l & 15, lh = l >> 4;
  int bm = blockIdx.x, bn = blockIdx.y;
  int sel = bn >> 3;
  int n0 = (bn & 7) * 128;
  const unsigned short* Bt = sel == 0 ? Wtq : (sel == 1 ? Wtk : Wtv);
  unsigned short* Out = sel == 0 ? Qb : (sel == 1 ? Kb : Vb);

  const unsigned short* Ag = A + (size_t)(bm * 128) * 1024;
  const unsigned short* Bg = Bt + (size_t)n0 * 1024;

  f32x4 acc[4][4];
  #pragma unroll
  for (int i = 0; i < 4; i++)
    #pragma unroll
    for (int j = 0; j < 4; j++) acc[i][j] = (f32x4){0.f, 0.f, 0.f, 0.f};

  int srow = w * 32 + (l >> 2);
  int sk = (l & 3) * 8;

  for (int k0 = 0; k0 < 1024; k0 += 32) {
    gll16(Ag + (size_t)srow * 1024 + k0 + sk,        As + w * 1024);
    gll16(Ag + (size_t)(srow + 16) * 1024 + k0 + sk, As + w * 1024 + 512);
    gll16(Bg + (size_t)srow * 1024 + k0 + sk,        Bs + w * 1024);
    gll16(Bg + (size_t)(srow + 16) * 1024 + k0 + sk, Bs + w * 1024 + 512);
    __syncthreads();
    bfx8 af[4], bfv[4];
    #pragma unroll
    for (int rt = 0; rt < 4; rt++) af[rt] = *(const bfx8*)&As[(wr * 64 + rt * 16 + lr) * 32 + lh * 8];
    #pragma unroll
    for (int ct = 0; ct < 4; ct++) bfv[ct] = *(const bfx8*)&Bs[(wc * 64 + ct * 16 + lr) * 32 + lh * 8];
    #pragma unroll
    for (int rt = 0; rt < 4; rt++)
      #pragma unroll
      for (int ct = 0; ct < 4; ct++)
        acc[rt][ct] = __builtin_amdgcn_mfma_f32_16x16x32_bf16(af[rt], bfv[ct], acc[rt][ct], 0, 0, 0);
    __syncthreads();
  }

  int row0 = bm * 128 + wr * 64;
  #pragma unroll
  for (int rt = 0; rt < 4; rt++)
    #pragma unroll
    for (int ct = 0; ct < 4; ct++)
      #pragma unroll
      for (int j = 0; j < 4; j++) {
        int r = row0 + rt * 16 + lh * 4 + j;
        int c = n0 + wc * 64 + ct * 16 + lr;
        Out[(size_t)r * 1024 + c] = f2bf(acc[rt][ct][j]);
      }
}

// ---------------- output projection GEMM + bias -> f32 ----------------
__global__ __launch_bounds__(256) void gemm_proj(
    const unsigned short* __restrict__ A, const unsigned short* __restrict__ Bt,
    const float* __restrict__ bias, float* __restrict__ Out) {
  __shared__ unsigned short As[128 * 32];
  __shared__ unsigned short Bs[128 * 32];
  int t = threadIdx.x;
  int w = t >> 6, l = t & 63;
  int wr = w >> 1, wc = w & 1;
  int lr = l & 15, lh = l >> 4;
  int bm = blockIdx.x, bn = blockIdx.y;
  int n0 = bn * 128;
  const unsigned short* Ag = A + (size_t)(bm * 128) * 1024;
  const unsigned short* Bg = Bt + (size_t)n0 * 1024;

  f32x4 acc[4][4];
  #pragma unroll
  for (int i = 0; i < 4; i++)
    #pragma unroll
    for (int j = 0; j < 4; j++) acc[i][j] = (f32x4){0.f, 0.f, 0.f, 0.f};

  int srow = w * 32 + (l >> 2);
  int sk = (l & 3) * 8;

  for (int k0 = 0; k0 < 1024; k0 += 32) {
    gll16(Ag + (size_t)srow * 1024 + k0 + sk,        As + w * 1024);
    gll16(Ag + (size_t)(srow + 16) * 1024 + k0 + sk, As + w * 1024 + 512);
    gll16(Bg + (size_t)srow * 1024 + k0 + sk,        Bs + w * 1024);
    gll16(Bg + (size_t)(srow + 16) * 1024 + k0 + sk, Bs + w * 1024 + 512);
    __syncthreads();
    bfx8 af[4], bfv[4];
    #pragma unroll
    for (int rt = 0; rt < 4; rt++) af[rt] = *(const bfx8*)&As[(wr * 64 + rt * 16 + lr) * 32 + lh * 8];
    #pragma unroll
    for (int ct = 0; ct < 4; ct++) bfv[ct] = *(const bfx8*)&Bs[(wc * 64 + ct * 16 + lr) * 32 + lh * 8];
    #pragma unroll
    for (int rt = 0; rt < 4; rt++)
      #pragma unroll
      for (int ct = 0; ct < 4; ct++)
        acc[rt][ct] = __builtin_amdgcn_mfma_f32_16x16x32_bf16(af[rt], bfv[ct], acc[rt][ct], 0, 0, 0);
    __syncthreads();
  }

  float bv[4];
  #pragma unroll
  for (int ct = 0; ct < 4; ct++) bv[ct] = bias[n0 + wc * 64 + ct * 16 + lr];

  int row0 = bm * 128 + wr * 64;
  #pragma unroll
  for (int rt = 0; rt < 4; rt++)
    #pragma unroll
    for (int ct = 0; ct < 4; ct++)
      #pragma unroll
      for (int j = 0; j < 4; j++) {
        int r = row0 + rt * 16 + lh * 4 + j;
        int c = n0 + wc * 64 + ct * 16 + lr;
        Out[(size_t)r * 1024 + c] = acc[rt][ct][j] + bv[ct];
      }
}

// ---------------- causal attention per (b,h): flash-style, in-register softmax ----------------
// LDS: Vt (V transposed, 2-way-conflict stride) + per-wave P chunk. 38KB -> 4 blocks/CU.
// No barriers in the main loop: P is wave-private, Vt read-only after staging.
__global__ __launch_bounds__(256) void attn_kernel(
    const unsigned short* __restrict__ Qb, const unsigned short* __restrict__ Kb,
    const unsigned short* __restrict__ Vb, unsigned short* __restrict__ Ab) {
  __shared__ unsigned short Vt[64][260];    // V^T [d][k], stride 520B = 130dw (2-way, free)
  __shared__ unsigned short Pw[4][16][36];  // per-wave P chunk [16 q][32 k + pad], 72B rows

  int t = threadIdx.x;
  int w = t >> 6, l = t & 63;
  int lr = l & 15, lh = l >> 4;
  int bh = blockIdx.x;
  size_t rowbase = (size_t)(bh >> 4) * 256 * 1024 + (size_t)(bh & 15) * 64;

  // stage V transposed
  {
    int rr = t >> 3, part = t & 7;
    for (int i = 0; i < 8; i++) {
      int row = i * 32 + rr;
      bfx8 vv = *(const bfx8*)(Vb + rowbase + (size_t)row * 1024 + part * 8);
      #pragma unroll
      for (int e = 0; e < 8; e++) Vt[part * 8 + e][row] = (unsigned short)vv[e];
    }
  }
  __syncthreads();

  for (int qt = 0; qt < 4; qt++) {
    int r0 = qt * 64 + w * 16;               // wave's first q row
    const unsigned short* Qrow = Qb + rowbase + (size_t)(r0 + lr) * 1024 + lh * 8;
    bfx8 aq0 = *(const bfx8*)(Qrow);
    bfx8 aq1 = *(const bfx8*)(Qrow + 32);

    float m[4], lsum[4];
    #pragma unroll
    for (int j = 0; j < 4; j++) { m[j] = -1e30f; lsum[j] = 0.f; }
    f32x4 oc[4];
    #pragma unroll
    for (int ct = 0; ct < 4; ct++) oc[ct] = (f32x4){0.f, 0.f, 0.f, 0.f};

    int nkc = ((r0 + 15) >> 5) + 1;          // 32-col causal chunk count
    for (int kc = 0; kc < nkc; kc++) {
      // ---- S chunk [16 q x 32 k]: K fragments straight from global (L1/L2-resident)
      const unsigned short* Kr = Kb + rowbase + (size_t)(kc * 32 + lr) * 1024 + lh * 8;
      bfx8 bk00 = *(const bfx8*)(Kr);
      bfx8 bk01 = *(const bfx8*)(Kr + 32);
      bfx8 bk10 = *(const bfx8*)(Kr + 16 * 1024);
      bfx8 bk11 = *(const bfx8*)(Kr + 16 * 1024 + 32);
      f32x4 s0 = (f32x4){0.f, 0.f, 0.f, 0.f};
      f32x4 s1 = (f32x4){0.f, 0.f, 0.f, 0.f};
      s0 = __builtin_amdgcn_mfma_f32_16x16x32_bf16(aq0, bk00, s0, 0, 0, 0);
      s0 = __builtin_amdgcn_mfma_f32_16x16x32_bf16(aq1, bk01, s0, 0, 0, 0);
      s1 = __builtin_amdgcn_mfma_f32_16x16x32_bf16(aq0, bk10, s1, 0, 0, 0);
      s1 = __builtin_amdgcn_mfma_f32_16x16x32_bf16(aq1, bk11, s1, 0, 0, 0);

      // ---- online softmax, fully in registers (shfl over the 16-lane row group)
      int c0 = kc * 32 + lr, c1 = c0 + 16;
      #pragma unroll
      for (int j = 0; j < 4; j++) {
        int row = r0 + lh * 4 + j;
        float v0 = (c0 <= row) ? s0[j] : -1e30f;
        float v1 = (c1 <= row) ? s1[j] : -1e30f;
        float cm = fmaxf(v0, v1);
        cm = fmaxf(cm, __shfl_xor(cm, 1));
        cm = fmaxf(cm, __shfl_xor(cm, 2));
        cm = fmaxf(cm, __shfl_xor(cm, 4));
        cm = fmaxf(cm, __shfl_xor(cm, 8));
        float mn = fmaxf(m[j], cm);
        float sc = __expf((m[j] - mn) * SCALE_ATT);
        float p0 = (c0 <= row) ? __expf((s0[j] - mn) * SCALE_ATT) : 0.f;
        float p1 = (c1 <= row) ? __expf((s1[j] - mn) * SCALE_ATT) : 0.f;
        m[j] = mn;
        float cs = p0 + p1;
        cs += __shfl_xor(cs, 1);
        cs += __shfl_xor(cs, 2);
        cs += __shfl_xor(cs, 4);
        cs += __shfl_xor(cs, 8);
        lsum[j] = lsum[j] * sc + cs;
        #pragma unroll
        for (int ct = 0; ct < 4; ct++) oc[ct][j] *= sc;
        Pw[w][lh * 4 + j][lr] = f2bf(p0);
        Pw[w][lh * 4 + j][16 + lr] = f2bf(p1);
      }

      // ---- PV for this chunk (same-wave LDS write->read: HW in-order DS, no barrier)
      bfx8 pa = ld2x64(&Pw[w][lr][lh * 8]);
      #pragma unroll
      for (int ct = 0; ct < 4; ct++) {
        bfx8 vb = ld2x64(&Vt[ct * 16 + lr][kc * 32 + lh * 8]);
        oc[ct] = __builtin_amdgcn_mfma_f32_16x16x32_bf16(pa, vb, oc[ct], 0, 0, 0);
      }
    }

    // ---- epilogue: fold 1/l, store bf16
    float rinv[4];
    #pragma unroll
    for (int j = 0; j < 4; j++) rinv[j] = 1.0f / lsum[j];
    #pragma unroll
    for (int ct = 0; ct < 4; ct++)
      #pragma unroll
      for (int j = 0; j < 4; j++) {
        int row = r0 + lh * 4 + j;
        Ab[rowbase + (size_t)row * 1024 + ct * 16 + lr] = f2bf(oc[ct][j] * rinv[j]);
      }
  }
}

extern "C" void kernel_launch(void* const* d_in, const int* in_sizes, int n_in,
                              void* d_out, int out_size, void* d_ws, size_t ws_size,
                              hipStream_t stream) {
  const float* x  = (const float*)d_in[0];
  const float* Wq = (const float*)d_in[1];
  const float* Wk = (const float*)d_in[2];
  const float* Wv = (const float*)d_in[3];
  const float* Wo = (const float*)d_in[4];
  const float* bo = (const float*)d_in[5];
  float* out = (float*)d_out;

  char* ws = (char*)d_ws;
  unsigned short* xb  = (unsigned short*)(ws);                          // 32MB (reused as Ab)
  unsigned short* Wtq = (unsigned short*)(ws + (size_t)(32u << 20));    // 2MB
  unsigned short* Wtk = (unsigned short*)(ws + (size_t)(34u << 20));
  unsigned short* Wtv = (unsigned short*)(ws + (size_t)(36u << 20));
  unsigned short* Wto = (unsigned short*)(ws + (size_t)(38u << 20));
  unsigned short* Qb  = (unsigned short*)(ws + (size_t)(40u << 20));    // 32MB
  unsigned short* Kb  = (unsigned short*)(ws + (size_t)(72u << 20));    // 32MB
  unsigned short* Vb  = (unsigned short*)(ws + (size_t)(104u << 20));   // 32MB
  unsigned short* Ab  = xb;  // x dead after gemm_qkv

  cvt_x<<<2048, 256, 0, stream>>>(x, xb, 4194304);
  cvt_w<<<dim3(16, 16, 4), 256, 0, stream>>>(Wq, Wk, Wv, Wo, Wtq, Wtk, Wtv, Wto);
  gemm_qkv<<<dim3(128, 24), 256, 0, stream>>>(xb, Wtq, Wtk, Wtv, Qb, Kb, Vb);
  attn_kernel<<<1024, 256, 0, stream>>>(Qb, Kb, Vb, Ab);
  gemm_proj<<<dim3(128, 8), 256, 0, stream>>>(Ab, Wto, bo, out);
}

// Round 5
// 224.249 us; speedup vs baseline: 2.1608x; 1.1472x over previous
//
#include <hip/hip_runtime.h>
#include <hip/hip_bf16.h>
#include <stdint.h>

typedef __attribute__((ext_vector_type(8))) short bfx8;
typedef __attribute__((ext_vector_type(4))) short bfx4;
typedef __attribute__((ext_vector_type(4))) float f32x4;
typedef __attribute__((ext_vector_type(4))) unsigned short us4;

#define SCALE_ATT 0.125f

__device__ __forceinline__ unsigned short f2bf(float f) {
  union { float f; unsigned u; } a; a.f = f;
  unsigned r = a.u + 0x7fffu + ((a.u >> 16) & 1u);
  return (unsigned short)(r >> 16);
}

__device__ __forceinline__ void gll16(const void* g, void* l) {
  __builtin_amdgcn_global_load_lds(
      (__attribute__((address_space(1))) void*)(g),
      (__attribute__((address_space(3))) void*)(l), 16, 0, 0);
}

__device__ __forceinline__ bfx8 ld2x64(const unsigned short* p) {
  bfx4 lo = *(const bfx4*)p;
  bfx4 hi = *(const bfx4*)(p + 4);
  return __builtin_shufflevector(lo, hi, 0, 1, 2, 3, 4, 5, 6, 7);
}

// ---------------- prepass: x f32 -> bf16 ----------------
__global__ __launch_bounds__(256) void cvt_x(const float* __restrict__ x,
                                             unsigned short* __restrict__ xb, int n4) {
  int i = blockIdx.x * blockDim.x + threadIdx.x;
  int stride = gridDim.x * blockDim.x;
  const float4* x4 = (const float4*)x;
  for (; i < n4; i += stride) {
    float4 v = x4[i];
    us4 o;
    o[0] = f2bf(v.x); o[1] = f2bf(v.y); o[2] = f2bf(v.z); o[3] = f2bf(v.w);
    *(us4*)&xb[(size_t)i * 4] = o;
  }
}

// ---------------- prepass: W f32 [K][N] -> Wt bf16 [N][K] (transpose) ----------------
__global__ __launch_bounds__(256) void cvt_w(const float* __restrict__ W0, const float* __restrict__ W1,
                                             const float* __restrict__ W2, const float* __restrict__ W3,
                                             unsigned short* __restrict__ T0, unsigned short* __restrict__ T1,
                                             unsigned short* __restrict__ T2, unsigned short* __restrict__ T3) {
  const float* W; unsigned short* T;
  switch (blockIdx.z) {
    case 0: W = W0; T = T0; break;
    case 1: W = W1; T = T1; break;
    case 2: W = W2; T = T2; break;
    default: W = W3; T = T3; break;
  }
  __shared__ unsigned short Ts[64][68];
  int k0 = blockIdx.x * 64, n0 = blockIdx.y * 64;
  int t = threadIdx.x;
  int lrow = t >> 4, c4 = t & 15;
  #pragma unroll
  for (int i = 0; i < 4; i++) {
    int row = lrow + i * 16;
    float4 v = *(const float4*)&W[(size_t)(k0 + row) * 1024 + n0 + c4 * 4];
    Ts[c4 * 4 + 0][row] = f2bf(v.x);
    Ts[c4 * 4 + 1][row] = f2bf(v.y);
    Ts[c4 * 4 + 2][row] = f2bf(v.z);
    Ts[c4 * 4 + 3][row] = f2bf(v.w);
  }
  __syncthreads();
  #pragma unroll
  for (int i = 0; i < 4; i++) {
    int nrow = lrow + i * 16;
    us4 v = *(const us4*)&Ts[nrow][c4 * 4];
    *(us4*)&T[(size_t)(n0 + nrow) * 1024 + k0 + c4 * 4] = v;
  }
}

// ---------------- 256x256 8-phase GEMM (m201-style), K=1024, BK=64 ----------------
// LDS: A/B tiles split into k-halves [256][32] bf16, double-buffered (128 KiB).
// st_16x32 swizzle applied BOTH sides: pre-swizzled global source for
// global_load_lds (linear LDS dest) + swizzled ds_read address.
// vmcnt ledger (2 loads per half-tile-stage per thread):
//   stage order per iter t (into buf cur^1): p0:Akh0  p1:Bkh0  p2:Akh1  p3:Bkh1
//   reads per iter t (from buf cur):  p0: A0s(qm0)+B0s  p1: A0s(qm1)
//                                     p2: A1s(qm0)+B1s  p3: A1s(qm1)
//   vmcnt(4) before closing barrier of p1 (drains kh1(t), read at p2) and
//   of p3 (drains kh0(t+1), read at p0 of t+1); 4 loads always in flight.
#define DS_BAR() __builtin_amdgcn_s_barrier()
#define LGKM0() do { asm volatile("s_waitcnt lgkmcnt(0)" ::: "memory"); \
                     __builtin_amdgcn_sched_barrier(0); } while (0)
#define VMW4() asm volatile("s_waitcnt vmcnt(4)" ::: "memory")
#define VMW0() asm volatile("s_waitcnt vmcnt(0)" ::: "memory")

#define STAGE(hs, gb, r0, kbyte) do { \
  const char* _g = (const char*)(gb) + (size_t)((r0) + srow) * 2048 + (size_t)(kbyte) + scolb; \
  gll16(_g, (hs) + w * 1024); \
  gll16(_g + 16 * 2048, (hs) + w * 1024 + 512); \
} while (0)

#define LOADA(dst, hs, qm) \
  _Pragma("unroll") for (int mi = 0; mi < 4; ++mi) \
    dst[mi] = *(const bfx8*)&(hs)[(wm * 128 + (qm) * 64 + mi * 16 + lr) * 32 + rcol];

#define LOADB(dst, hs) \
  _Pragma("unroll") for (int ni = 0; ni < 4; ++ni) \
    dst[ni] = *(const bfx8*)&(hs)[(wn * 64 + ni * 16 + lr) * 32 + rcol];

#define MFMA16(rb, a, b) \
  _Pragma("unroll") for (int mi = 0; mi < 4; ++mi) \
    _Pragma("unroll") for (int ni = 0; ni < 4; ++ni) \
      acc[(rb) + mi][ni] = __builtin_amdgcn_mfma_f32_16x16x32_bf16(a[mi], b[ni], acc[(rb) + mi][ni], 0, 0, 0);

template<int MODE>  // 0: bf16 out, 3-way weight select (QKV). 1: f32 out + bias (proj)
__global__ __launch_bounds__(512, 2) void gemm8p(
    const unsigned short* __restrict__ A,
    const unsigned short* __restrict__ Bt0, const unsigned short* __restrict__ Bt1,
    const unsigned short* __restrict__ Bt2,
    unsigned short* __restrict__ O0, unsigned short* __restrict__ O1,
    unsigned short* __restrict__ O2,
    const float* __restrict__ bias, float* __restrict__ OutF, int nby) {
  __shared__ unsigned short A0s[2][256 * 32];
  __shared__ unsigned short B0s[2][256 * 32];
  __shared__ unsigned short A1s[2][256 * 32];
  __shared__ unsigned short B1s[2][256 * 32];

  int tid = threadIdx.x;
  int w = tid >> 6, l = tid & 63;
  int lr = l & 15, lh = l >> 4;
  int wm = w >> 2, wn = w & 3;
  // staging: thread covers rows srow, srow+16 (64B each) of a [256][32] half
  int srow = w * 32 + (l >> 2);
  int scolb = ((l & 3) * 16) ^ (((l >> 5) & 1) << 5);   // pre-swizzled global col bytes
  int rcol = (lh * 8) ^ (((lr >> 3) & 1) << 4);         // swizzled ds_read col elems

  // bijective XCD swizzle (nwg % 8 == 0)
  int cpx = gridDim.x >> 3;
  int o = blockIdx.x;
  int wg = (o & 7) * cpx + (o >> 3);
  int bm = wg / nby, bn = wg % nby;

  const unsigned short* Bt;
  unsigned short* Ob = nullptr;
  int n0;
  if (MODE == 0) {
    int sel = bn >> 2;
    n0 = (bn & 3) * 256;
    Bt = sel == 0 ? Bt0 : (sel == 1 ? Bt1 : Bt2);
    Ob = sel == 0 ? O0 : (sel == 1 ? O1 : O2);
  } else {
    Bt = Bt0;
    n0 = bn * 256;
  }
  int am0 = bm * 256;

  f32x4 acc[8][4];
  #pragma unroll
  for (int i = 0; i < 8; ++i)
    #pragma unroll
    for (int jj = 0; jj < 4; ++jj) acc[i][jj] = (f32x4){0.f, 0.f, 0.f, 0.f};

  bfx8 af[4], bf0[4], bf1[4];

  // prologue: stage tile 0 into buf 0 (issue order defines the vmcnt ledger)
  STAGE(A0s[0], A, am0, 0);   __builtin_amdgcn_sched_barrier(0);
  STAGE(B0s[0], Bt, n0, 0);   __builtin_amdgcn_sched_barrier(0);
  STAGE(A1s[0], A, am0, 64);  __builtin_amdgcn_sched_barrier(0);
  STAGE(B1s[0], Bt, n0, 64);  __builtin_amdgcn_sched_barrier(0);
  VMW4();               // kh0 pair landed; kh1 pair still in flight
  DS_BAR();

  int cur = 0;
  #pragma unroll 1
  for (int t = 0; t < 15; ++t) {
    int kb = (t + 1) * 128;
    // ---- phase 0: (qm0, ks0)
    LOADA(af, A0s[cur], 0);
    LOADB(bf0, B0s[cur]);
    STAGE(A0s[cur ^ 1], A, am0, kb);
    DS_BAR(); LGKM0();
    __builtin_amdgcn_s_setprio(1);
    MFMA16(0, af, bf0);
    __builtin_amdgcn_s_setprio(0);
    DS_BAR();
    // ---- phase 1: (qm1, ks0)
    LOADA(af, A0s[cur], 1);
    STAGE(B0s[cur ^ 1], Bt, n0, kb);
    DS_BAR(); LGKM0();
    __builtin_amdgcn_s_setprio(1);
    MFMA16(4, af, bf0);
    __builtin_amdgcn_s_setprio(0);
    VMW4();             // drain kh1(t) (read next phase); kh0(t+1) stays in flight
    DS_BAR();
    // ---- phase 2: (qm0, ks1)
    LOADA(af, A1s[cur], 0);
    LOADB(bf1, B1s[cur]);
    STAGE(A1s[cur ^ 1], A, am0, kb + 64);
    DS_BAR(); LGKM0();
    __builtin_amdgcn_s_setprio(1);
    MFMA16(0, af, bf1);
    __builtin_amdgcn_s_setprio(0);
    DS_BAR();
    // ---- phase 3: (qm1, ks1)
    LOADA(af, A1s[cur], 1);
    STAGE(B1s[cur ^ 1], Bt, n0, kb + 64);
    DS_BAR(); LGKM0();
    __builtin_amdgcn_s_setprio(1);
    MFMA16(4, af, bf1);
    __builtin_amdgcn_s_setprio(0);
    VMW4();             // drain kh0(t+1) (read at p0 of t+1); kh1(t+1) in flight
    DS_BAR();
    cur ^= 1;
  }
  // ---- final tile (t = 15): no staging; kh0 already drained by loop-end VMW4
  LOADA(af, A0s[cur], 0);
  LOADB(bf0, B0s[cur]);
  DS_BAR(); LGKM0();
  __builtin_amdgcn_s_setprio(1);
  MFMA16(0, af, bf0);
  __builtin_amdgcn_s_setprio(0);
  DS_BAR();
  LOADA(af, A0s[cur], 1);
  DS_BAR(); LGKM0();
  __builtin_amdgcn_s_setprio(1);
  MFMA16(4, af, bf0);
  __builtin_amdgcn_s_setprio(0);
  VMW0();               // drain kh1(15) before reading it (all waves, then barrier)
  DS_BAR();
  LOADA(af, A1s[cur], 0);
  LOADB(bf1, B1s[cur]);
  DS_BAR(); LGKM0();
  __builtin_amdgcn_s_setprio(1);
  MFMA16(0, af, bf1);
  __builtin_amdgcn_s_setprio(0);
  DS_BAR();
  LOADA(af, A1s[cur], 1);
  LGKM0();
  __builtin_amdgcn_s_setprio(1);
  MFMA16(4, af, bf1);
  __builtin_amdgcn_s_setprio(0);

  // ---- epilogue
  #pragma unroll
  for (int mi8 = 0; mi8 < 8; ++mi8)
    #pragma unroll
    for (int ni = 0; ni < 4; ++ni)
      #pragma unroll
      for (int j = 0; j < 4; ++j) {
        int r = am0 + wm * 128 + mi8 * 16 + lh * 4 + j;
        int c = n0 + wn * 64 + ni * 16 + lr;
        if (MODE == 0)
          Ob[(size_t)r * 1024 + c] = f2bf(acc[mi8][ni][j]);
        else
          OutF[(size_t)r * 1024 + c] = acc[mi8][ni][j] + bias[c];
      }
}

// ---------------- causal attention per (b,h): flash-style, in-register softmax ----------------
__global__ __launch_bounds__(256) void attn_kernel(
    const unsigned short* __restrict__ Qb, const unsigned short* __restrict__ Kb,
    const unsigned short* __restrict__ Vb, unsigned short* __restrict__ Ab) {
  __shared__ unsigned short Vt[64][260];    // V^T [d][k], stride 520B = 130dw (2-way, free)
  __shared__ unsigned short Pw[4][16][36];  // per-wave P chunk [16 q][32 k + pad]

  int t = threadIdx.x;
  int w = t >> 6, l = t & 63;
  int lr = l & 15, lh = l >> 4;
  int bh = blockIdx.x;
  size_t rowbase = (size_t)(bh >> 4) * 256 * 1024 + (size_t)(bh & 15) * 64;

  {
    int rr = t >> 3, part = t & 7;
    for (int i = 0; i < 8; i++) {
      int row = i * 32 + rr;
      bfx8 vv = *(const bfx8*)(Vb + rowbase + (size_t)row * 1024 + part * 8);
      #pragma unroll
      for (int e = 0; e < 8; e++) Vt[part * 8 + e][row] = (unsigned short)vv[e];
    }
  }
  __syncthreads();

  for (int qt = 0; qt < 4; qt++) {
    int r0 = qt * 64 + w * 16;
    const unsigned short* Qrow = Qb + rowbase + (size_t)(r0 + lr) * 1024 + lh * 8;
    bfx8 aq0 = *(const bfx8*)(Qrow);
    bfx8 aq1 = *(const bfx8*)(Qrow + 32);

    float m[4], lsum[4];
    #pragma unroll
    for (int j = 0; j < 4; j++) { m[j] = -1e30f; lsum[j] = 0.f; }
    f32x4 oc[4];
    #pragma unroll
    for (int ct = 0; ct < 4; ct++) oc[ct] = (f32x4){0.f, 0.f, 0.f, 0.f};

    int nkc = ((r0 + 15) >> 5) + 1;
    for (int kc = 0; kc < nkc; kc++) {
      const unsigned short* Kr = Kb + rowbase + (size_t)(kc * 32 + lr) * 1024 + lh * 8;
      bfx8 bk00 = *(const bfx8*)(Kr);
      bfx8 bk01 = *(const bfx8*)(Kr + 32);
      bfx8 bk10 = *(const bfx8*)(Kr + 16 * 1024);
      bfx8 bk11 = *(const bfx8*)(Kr + 16 * 1024 + 32);
      f32x4 s0 = (f32x4){0.f, 0.f, 0.f, 0.f};
      f32x4 s1 = (f32x4){0.f, 0.f, 0.f, 0.f};
      s0 = __builtin_amdgcn_mfma_f32_16x16x32_bf16(aq0, bk00, s0, 0, 0, 0);
      s0 = __builtin_amdgcn_mfma_f32_16x16x32_bf16(aq1, bk01, s0, 0, 0, 0);
      s1 = __builtin_amdgcn_mfma_f32_16x16x32_bf16(aq0, bk10, s1, 0, 0, 0);
      s1 = __builtin_amdgcn_mfma_f32_16x16x32_bf16(aq1, bk11, s1, 0, 0, 0);

      int c0 = kc * 32 + lr, c1 = c0 + 16;
      #pragma unroll
      for (int j = 0; j < 4; j++) {
        int row = r0 + lh * 4 + j;
        float v0 = (c0 <= row) ? s0[j] : -1e30f;
        float v1 = (c1 <= row) ? s1[j] : -1e30f;
        float cm = fmaxf(v0, v1);
        cm = fmaxf(cm, __shfl_xor(cm, 1));
        cm = fmaxf(cm, __shfl_xor(cm, 2));
        cm = fmaxf(cm, __shfl_xor(cm, 4));
        cm = fmaxf(cm, __shfl_xor(cm, 8));
        float mn = fmaxf(m[j], cm);
        float sc = __expf((m[j] - mn) * SCALE_ATT);
        float p0 = (c0 <= row) ? __expf((s0[j] - mn) * SCALE_ATT) : 0.f;
        float p1 = (c1 <= row) ? __expf((s1[j] - mn) * SCALE_ATT) : 0.f;
        m[j] = mn;
        float cs = p0 + p1;
        cs += __shfl_xor(cs, 1);
        cs += __shfl_xor(cs, 2);
        cs += __shfl_xor(cs, 4);
        cs += __shfl_xor(cs, 8);
        lsum[j] = lsum[j] * sc + cs;
        #pragma unroll
        for (int ct = 0; ct < 4; ct++) oc[ct][j] *= sc;
        Pw[w][lh * 4 + j][lr] = f2bf(p0);
        Pw[w][lh * 4 + j][16 + lr] = f2bf(p1);
      }

      bfx8 pa = ld2x64(&Pw[w][lr][lh * 8]);
      #pragma unroll
      for (int ct = 0; ct < 4; ct++) {
        bfx8 vb = ld2x64(&Vt[ct * 16 + lr][kc * 32 + lh * 8]);
        oc[ct] = __builtin_amdgcn_mfma_f32_16x16x32_bf16(pa, vb, oc[ct], 0, 0, 0);
      }
    }

    float rinv[4];
    #pragma unroll
    for (int j = 0; j < 4; j++) rinv[j] = 1.0f / lsum[j];
    #pragma unroll
    for (int ct = 0; ct < 4; ct++)
      #pragma unroll
      for (int j = 0; j < 4; j++) {
        int row = r0 + lh * 4 + j;
        Ab[rowbase + (size_t)row * 1024 + ct * 16 + lr] = f2bf(oc[ct][j] * rinv[j]);
      }
  }
}

extern "C" void kernel_launch(void* const* d_in, const int* in_sizes, int n_in,
                              void* d_out, int out_size, void* d_ws, size_t ws_size,
                              hipStream_t stream) {
  const float* x  = (const float*)d_in[0];
  const float* Wq = (const float*)d_in[1];
  const float* Wk = (const float*)d_in[2];
  const float* Wv = (const float*)d_in[3];
  const float* Wo = (const float*)d_in[4];
  const float* bo = (const float*)d_in[5];
  float* out = (float*)d_out;

  char* ws = (char*)d_ws;
  unsigned short* xb  = (unsigned short*)(ws);                          // 32MB (reused as Ab)
  unsigned short* Wtq = (unsigned short*)(ws + (size_t)(32u << 20));    // 2MB
  unsigned short* Wtk = (unsigned short*)(ws + (size_t)(34u << 20));
  unsigned short* Wtv = (unsigned short*)(ws + (size_t)(36u << 20));
  unsigned short* Wto = (unsigned short*)(ws + (size_t)(38u << 20));
  unsigned short* Qb  = (unsigned short*)(ws + (size_t)(40u << 20));    // 32MB
  unsigned short* Kb  = (unsigned short*)(ws + (size_t)(72u << 20));    // 32MB
  unsigned short* Vb  = (unsigned short*)(ws + (size_t)(104u << 20));   // 32MB
  unsigned short* Ab  = xb;  // x dead after gemm_qkv

  cvt_x<<<2048, 256, 0, stream>>>(x, xb, 4194304);
  cvt_w<<<dim3(16, 16, 4), 256, 0, stream>>>(Wq, Wk, Wv, Wo, Wtq, Wtk, Wtv, Wto);
  gemm8p<0><<<768, 512, 0, stream>>>(xb, Wtq, Wtk, Wtv, Qb, Kb, Vb, nullptr, nullptr, 12);
  attn_kernel<<<1024, 256, 0, stream>>>(Qb, Kb, Vb, Ab);
  gemm8p<1><<<256, 512, 0, stream>>>(Ab, Wto, Wto, Wto, nullptr, nullptr, nullptr, bo, out, 4);
}